// Round 11
// baseline (34.936 us; speedup 1.0000x reference)
//
#include <hip/hip_runtime.h>

#define HW 2112L            // 64*33
typedef float f32x4 __attribute__((ext_vector_type(4)));
typedef short s16x8 __attribute__((ext_vector_type(8)));

// ws: W B-fragment planes. 512 modes * 2 ntiles * 64 lanes * 8 bf16 * 2B = 1 MB/plane.
#define WT_PLANE 1048576L
#define OFF_WHR 0L
#define OFF_WLR (WT_PLANE)
#define OFF_WHI (2*WT_PLANE)
#define OFF_WLI (3*WT_PLANE)

__device__ __forceinline__ ushort f2bf(float f) {
    unsigned u = __float_as_uint(f);
    u += 0x7FFF + ((u >> 16) & 1);          // RNE to bf16
    return (ushort)(u >> 16);
}
__device__ __forceinline__ void split_bf(float v, ushort& hi, ushort& lo) {
    hi = f2bf(v);
    float hf = __uint_as_float(((unsigned)hi) << 16);
    lo = f2bf(v - hf);
}

// =============== K1: W -> B-frag planes (64 blocks, ~2us serial prefix) ===============
// block=(r,i,nt); thread=(col=tid>>4, j=tid&15) -> j-fastest coalesced reads.
__global__ __launch_bounds__(256) void w_prep(
    const float* __restrict__ w1_re, const float* __restrict__ w1_im,
    const float* __restrict__ w2_re, const float* __restrict__ w2_im,
    char* __restrict__ ws)
{
    const int tid = threadIdx.x, bid = blockIdx.x;
    const int r = bid >> 5, i = (bid >> 1) & 15, nt = bid & 1;
    const float* wre = r ? w2_re : w1_re;
    const float* wim = r ? w2_im : w1_im;
    const int col = tid >> 4, j = tid & 15, o = nt * 16 + col;
    const int modeLin = (r * 16 + i) * 16 + j;
    s16x8* phr = (s16x8*)(ws + OFF_WHR);
    s16x8* plr = (s16x8*)(ws + OFF_WLR);
    s16x8* phi = (s16x8*)(ws + OFF_WHI);
    s16x8* pli = (s16x8*)(ws + OFF_WLI);
    #pragma unroll
    for (int kg = 0; kg < 4; ++kg) {
        s16x8 hr, lr, hi2, li2;
        #pragma unroll
        for (int e = 0; e < 8; ++e) {
            int c = kg * 8 + e;
            long src = ((long)(c * 32 + o) * 16 + i) * 16 + j;
            ushort a, b;
            split_bf(wre[src], a, b); hr[e] = (short)a; lr[e] = (short)b;
            split_bf(wim[src], a, b); hi2[e] = (short)a; li2[e] = (short)b;
        }
        long off = (long)(modeLin * 2 + nt) * 64 + kg * 16 + col;
        phr[off] = hr; plr[off] = lr; phi[off] = hi2; pli[off] = li2;
    }
}

// =============== K2: compute (1024 blocks) + middle-band fill (256 blocks) ===============
// compute block=(r,i,bt), bltile=4. LDS 25.6KB -> 6 blocks/CU, 24 waves/CU.
// A-path: x staged as bf16-hi frags in LDS ([j][bl][c], c contiguous) ->
// gather = 2x ds_read_b128 per jj. 2-term products (A-lo dropped).
__global__ __launch_bounds__(256, 6) void k2_compute(
    const float* __restrict__ x_re, const float* __restrict__ x_im,
    float* __restrict__ out, const char* __restrict__ ws)
{
    const int tid = threadIdx.x, bid = blockIdx.x;

    __shared__ __align__(16) ushort xfr[16][4][32];   // [j][bl][c] bf16 hi of re, 4KB
    __shared__ __align__(16) ushort xfi[16][4][32];   // bf16 hi of im, 4KB
    __shared__ __align__(16) float2 stg[128][17];     // 17.4KB

    if (bid >= 1024) {
        // ---- fill role: middle band h in [16,48) ----
        const int fid = bid - 1024;               // [0,256)
        int gtid = fid * 256 + tid, n = 256 * 256;
        float4* out4 = (float4*)out;
        const float4 z = make_float4(0.f, 0.f, 0.f, 0.f);
        for (int idx = gtid; idx < 4096 * 528; idx += n) {
            int plane = idx / 528;
            int k = idx - plane * 528;
            out4[(long)plane * 1056 + 264 + k] = z;
        }
        return;
    }

    const int r = bid >> 9, i = (bid >> 5) & 15, bt = bid & 31;
    const int h = r ? 48 + i : i;
    const int bl0 = bt * 4;
    const int modeBase = (r * 16 + i) * 16;

    // ---- stage x[bl0..+4, all c, h, j<16]: coalesced 16-float runs, bf16-split now ----
    #pragma unroll
    for (int p = 0; p < 2; ++p) {
        int idx = p * 256 + tid;            // [0,512)
        int j4 = idx & 3, row = idx >> 2;   // row: c=row>>2, bl=row&3
        int c = row >> 2, bl = row & 3;
        long base = ((long)((bl0 + bl) * 32 + c)) * HW + h * 33 + j4 * 4;
        float re0 = x_re[base + 0], re1 = x_re[base + 1], re2 = x_re[base + 2], re3 = x_re[base + 3];
        float im0 = x_im[base + 0], im1 = x_im[base + 1], im2 = x_im[base + 2], im3 = x_im[base + 3];
        xfr[j4 * 4 + 0][bl][c] = f2bf(re0); xfi[j4 * 4 + 0][bl][c] = f2bf(im0);
        xfr[j4 * 4 + 1][bl][c] = f2bf(re1); xfi[j4 * 4 + 1][bl][c] = f2bf(im1);
        xfr[j4 * 4 + 2][bl][c] = f2bf(re2); xfi[j4 * 4 + 2][bl][c] = f2bf(im2);
        xfr[j4 * 4 + 3][bl][c] = f2bf(re3); xfi[j4 * 4 + 3][bl][c] = f2bf(im3);
    }
    __syncthreads();

    const int wave = tid >> 6, lane = tid & 63;
    const int m = lane & 3, ks = lane >> 4, colo = lane & 15;

    const s16x8* Bwhr = (const s16x8*)(ws + OFF_WHR);
    const s16x8* Bwlr = (const s16x8*)(ws + OFF_WLR);
    const s16x8* Bwhi = (const s16x8*)(ws + OFF_WHI);
    const s16x8* Bwli = (const s16x8*)(ws + OFF_WLI);

    #pragma unroll
    for (int jj = 0; jj < 4; ++jj) {
        const int j = wave * 4 + jj;
        const int modeLin = modeBase + j;

        // A-frags: 2x ds_read_b128 (2-way bank aliasing = free)
        s16x8 Ahr = *(const s16x8*)&xfr[j][m][ks * 8];
        s16x8 Ahi = *(const s16x8*)&xfi[j][m][ks * 8];

        #pragma unroll
        for (int nt = 0; nt < 2; ++nt) {
            long boff = (long)(modeLin * 2 + nt) * 64 + lane;
            s16x8 Bhr = Bwhr[boff], Blr = Bwlr[boff];
            s16x8 Bhi = Bwhi[boff], Bli = Bwli[boff];

            f32x4 accP = (f32x4)0.0f, accN = (f32x4)0.0f, accI = (f32x4)0.0f;
            accP = __builtin_amdgcn_mfma_f32_16x16x32_bf16(Ahr, Bhr, accP, 0, 0, 0);
            accP = __builtin_amdgcn_mfma_f32_16x16x32_bf16(Ahr, Blr, accP, 0, 0, 0);
            accN = __builtin_amdgcn_mfma_f32_16x16x32_bf16(Ahi, Bhi, accN, 0, 0, 0);
            accN = __builtin_amdgcn_mfma_f32_16x16x32_bf16(Ahi, Bli, accN, 0, 0, 0);
            accI = __builtin_amdgcn_mfma_f32_16x16x32_bf16(Ahr, Bhi, accI, 0, 0, 0);
            accI = __builtin_amdgcn_mfma_f32_16x16x32_bf16(Ahr, Bli, accI, 0, 0, 0);
            accI = __builtin_amdgcn_mfma_f32_16x16x32_bf16(Ahi, Bhr, accI, 0, 0, 0);
            accI = __builtin_amdgcn_mfma_f32_16x16x32_bf16(Ahi, Blr, accI, 0, 0, 0);

            // D: col=lane&15 (o), row=ks*4+q (bl=q); rows repeat every 4 -> ks==0 stores
            if (ks == 0) {
                #pragma unroll
                for (int q = 0; q < 4; ++q)
                    stg[q * 32 + nt * 16 + colo][j] =
                        make_float2(accP[q] - accN[q], accI[q]);
            }
        }
    }
    __syncthreads();

    // ---- row-contiguous write-out: 128 rows x 33 float2, tail zeros fused ----
    float2* out2 = (float2*)out;
    #pragma unroll 2
    for (int t = 0; t < 17; ++t) {
        int idx = t * 256 + tid;              // [0, 4352); valid < 4224
        if (idx < 128 * 33) {
            int row = idx / 33;               // bl*32 + o
            int k = idx - row * 33;
            float2 v = (k < 16) ? stg[row][k] : make_float2(0.f, 0.f);
            long dst = ((long)(bl0 * 32 + row) * 64 + h) * 33 + k;
            out2[dst] = v;
        }
    }
}

extern "C" void kernel_launch(void* const* d_in, const int* in_sizes, int n_in,
                              void* d_out, int out_size, void* d_ws, size_t ws_size,
                              hipStream_t stream) {
    const float* x_re  = (const float*)d_in[0];
    const float* x_im  = (const float*)d_in[1];
    const float* w1_re = (const float*)d_in[2];
    const float* w1_im = (const float*)d_in[3];
    const float* w2_re = (const float*)d_in[4];
    const float* w2_im = (const float*)d_in[5];
    float* out = (float*)d_out;
    char* ws = (char*)d_ws;

    w_prep<<<dim3(64), dim3(256), 0, stream>>>(w1_re, w1_im, w2_re, w2_im, ws);
    k2_compute<<<dim3(1280), dim3(256), 0, stream>>>(x_re, x_im, out, ws);
}